// Round 1
// 4468.620 us; speedup vs baseline: 1.2376x; 1.2376x over previous
//
#include <hip/hip_runtime.h>
#include <math.h>

#define BSZ 2048
#define DIM 2048
#define MS 6
#define NIT 29          // k = 1..29
#define LAMREG 1e-4f
#define XROWS (MS*DIM)  // 12288: row stride of the (bsz, 6, d) layouts

typedef __bf16 bf16x8 __attribute__((ext_vector_type(8)));
typedef __bf16 bf16x4 __attribute__((ext_vector_type(4)));
typedef float  f32x4  __attribute__((ext_vector_type(4)));

__device__ __forceinline__ void async16(const void* g, void* l) {
    __builtin_amdgcn_global_load_lds((const __attribute__((address_space(1))) void*)g,
                                     (__attribute__((address_space(3))) void*)l, 16, 0, 0);
}

// swizzled LDS element offset for 16B chunk q (0..3) of row r in a [rows][32] bf16 panel
__device__ __forceinline__ int swz(int r, int q) {
    return r * 32 + ((q ^ ((r >> 1) & 3)) << 3);
}

// ---------------------------------------------------------------------------
// init: X[:,0] = x0, split-bf16 copy of x0, zero norms
// ---------------------------------------------------------------------------
__global__ __launch_bounds__(256) void init_kernel(const float* __restrict__ x0,
                                                   float* __restrict__ Xout,
                                                   __bf16* __restrict__ Ahi,
                                                   __bf16* __restrict__ Alo,
                                                   float* __restrict__ norms) {
    int idx = blockIdx.x * 256 + threadIdx.x;
    if (idx < 2 * NIT) norms[idx] = 0.0f;
    for (int i = idx; i < BSZ * DIM; i += gridDim.x * 256) {
        int b = i >> 11;
        int j = i & (DIM - 1);
        float v = x0[i];
        Xout[(size_t)b * XROWS + j] = v;
        __bf16 h = (__bf16)v;
        Ahi[i] = h;
        Alo[i] = (__bf16)(v - (float)h);
    }
}

// ---------------------------------------------------------------------------
// W (K x N, f32) -> W^T split into bf16 hi/lo:  WT[n][k] = W[k][n]
// ---------------------------------------------------------------------------
__global__ __launch_bounds__(256) void wt_split_kernel(const float* __restrict__ W,
                                                       __bf16* __restrict__ WThi,
                                                       __bf16* __restrict__ WTlo) {
    __shared__ float tile[32][33];
    const int tx = threadIdx.x & 31;
    const int ty = threadIdx.x >> 5;
    const int n0 = blockIdx.x * 32;
    const int k0 = blockIdx.y * 32;
#pragma unroll
    for (int i = 0; i < 32; i += 8)
        tile[ty + i][tx] = W[(size_t)(k0 + ty + i) * DIM + n0 + tx];
    __syncthreads();
#pragma unroll
    for (int i = 0; i < 32; i += 8) {
        float v = tile[tx][ty + i];
        __bf16 h = (__bf16)v;
        size_t o = (size_t)(n0 + ty + i) * DIM + k0 + tx;
        WThi[o] = h;
        WTlo[o] = (__bf16)(v - (float)h);
    }
}

// ---------------------------------------------------------------------------
// split-bf16 MFMA GEMM, double-buffered swizzled LDS.
// R1: 128x64 tiles, grid 512 -> 2 blocks/CU (was 128x128, grid 256 = 1/CU).
// At N=2048 the old config had 1 wave/SIMD: every __syncthreads' vmcnt(0)
// drain stalled the whole SIMD. Two co-resident blocks overlap drain/compute.
// Epilogue: F[:,up] = tanh(xnew@W + b); G[:,up] = f - x; optional norms.
// ---------------------------------------------------------------------------
__global__ __launch_bounds__(256, 2) void gemm_mfma_kernel(
    const __bf16* __restrict__ Ahi, const __bf16* __restrict__ Alo,
    const __bf16* __restrict__ WThi, const __bf16* __restrict__ WTlo,
    const float* __restrict__ bias,
    const float* __restrict__ Xbase, float* __restrict__ Fbase,
    float* __restrict__ Gbase, int up,
    float* __restrict__ normAcc, int doNorm)
{
    __shared__ __align__(16) __bf16 Ah[2][128 * 32];
    __shared__ __align__(16) __bf16 Al[2][128 * 32];
    __shared__ __align__(16) __bf16 Bh[2][64 * 32];
    __shared__ __align__(16) __bf16 Bl[2][64 * 32];
    __shared__ float rs[8];

    // XCD-aware swizzle over the 16x32 tile grid: each XCD (id&7) gets an
    // 8x8 rectangle -> its blocks share 8 A-panels + 8 B-panels.
    const int id = blockIdx.x;
    const int xcd = id & 7;
    const int slot = id >> 3;                        // 0..63
    const int by = ((xcd & 1) << 3) | (slot & 7);    // 0..15
    const int bx = ((xcd >> 1) << 3) | (slot >> 3);  // 0..31
    const int m0 = by * 128;
    const int n0 = bx * 64;

    const int tid = threadIdx.x;
    const int l = tid & 63;
    const int w = tid >> 6;
    const int wm = (w & 1) * 64;    // wave's 64-row half of the 128-row tile
    const int wn = (w >> 1) * 32;   // wave's 32-col half of the 64-col tile
    const int rl = l & 15;
    const int quad = l >> 4;

    // staging: lane l of wave w covers row w*16 + (l>>2) (+64 for A group 1),
    // LDS chunk position (l&3); load the XOR-swizzled global chunk so that
    // LDS position (row, c) holds global chunk c ^ ((row>>1)&3).
    const int srow = w * 16 + (l >> 2);
    const int gchunk = (l & 3) ^ ((l >> 3) & 3);
    const int scol = gchunk << 3;
    const size_t aoff = (size_t)(m0 + srow) * DIM + scol;
    const size_t boff = (size_t)(n0 + srow) * DIM + scol;
    const int lo = w * 512;

    f32x4 acc[4][2];
#pragma unroll
    for (int t = 0; t < 4; t++)
#pragma unroll
        for (int u = 0; u < 2; u++) acc[t][u] = (f32x4){0.f, 0.f, 0.f, 0.f};

    auto stage = [&](int kb, int s) {
        async16(Ahi + aoff + kb, &Ah[s][lo]);
        async16(Ahi + aoff + (size_t)64 * DIM + kb, &Ah[s][lo + 2048]);
        async16(Alo + aoff + kb, &Al[s][lo]);
        async16(Alo + aoff + (size_t)64 * DIM + kb, &Al[s][lo + 2048]);
        async16(WThi + boff + kb, &Bh[s][lo]);
        async16(WTlo + boff + kb, &Bl[s][lo]);
    };
    auto compute = [&](int s) {
        bf16x8 ah[4], al[4];
#pragma unroll
        for (int t = 0; t < 4; t++) {
            const int r = wm + t * 16 + rl;
            ah[t] = *(const bf16x8*)&Ah[s][swz(r, quad)];
            al[t] = *(const bf16x8*)&Al[s][swz(r, quad)];
        }
#pragma unroll
        for (int u = 0; u < 2; u++) {
            const int c = wn + u * 16 + rl;
            bf16x8 bh = *(const bf16x8*)&Bh[s][swz(c, quad)];
            bf16x8 bl = *(const bf16x8*)&Bl[s][swz(c, quad)];
#pragma unroll
            for (int t = 0; t < 4; t++) {
                acc[t][u] = __builtin_amdgcn_mfma_f32_16x16x32_bf16(ah[t], bh, acc[t][u], 0, 0, 0);
                acc[t][u] = __builtin_amdgcn_mfma_f32_16x16x32_bf16(al[t], bh, acc[t][u], 0, 0, 0);
                acc[t][u] = __builtin_amdgcn_mfma_f32_16x16x32_bf16(ah[t], bl, acc[t][u], 0, 0, 0);
            }
        }
    };

    stage(0, 0);
    for (int k0 = 0; k0 < DIM; k0 += 64) {
        __syncthreads();               // drains buf0 loads (issued one phase ago)
        stage(k0 + 32, 1);
        compute(0);
        __syncthreads();               // drains buf1 loads
        if (k0 + 64 < DIM) stage(k0 + 64, 0);
        compute(1);
    }

    // -------------------- epilogue --------------------
    int cols[2]; float bv[2];
#pragma unroll
    for (int u = 0; u < 2; u++) {
        cols[u] = n0 + wn + u * 16 + rl;
        bv[u] = bias[cols[u]];
    }
    float s1 = 0.0f, s2 = 0.0f;
#pragma unroll
    for (int t = 0; t < 4; t++) {
#pragma unroll
        for (int r = 0; r < 4; r++) {
            const int row = m0 + wm + t * 16 + quad * 4 + r;
            const size_t base = (size_t)row * XROWS + (size_t)up * DIM;
#pragma unroll
            for (int u = 0; u < 2; u++) {
                float v = tanhf(acc[t][u][r] + bv[u]);
                float xv = Xbase[base + cols[u]];
                float g = v - xv;
                Fbase[base + cols[u]] = v;
                if (Gbase) Gbase[base + cols[u]] = g;
                if (doNorm) { s1 = fmaf(g, g, s1); s2 = fmaf(v, v, s2); }
            }
        }
    }
    if (doNorm) {
#pragma unroll
        for (int off = 32; off > 0; off >>= 1) {
            s1 += __shfl_down(s1, off);
            s2 += __shfl_down(s2, off);
        }
        if (l == 0) { rs[w * 2] = s1; rs[w * 2 + 1] = s2; }
        __syncthreads();
        if (tid == 0) {
            atomicAdd(&normAcc[0], rs[0] + rs[2] + rs[4] + rs[6]);
            atomicAdd(&normAcc[1], rs[1] + rs[3] + rs[5] + rs[7]);
        }
    }
}

// ---------------------------------------------------------------------------
// fused Gram-row + solve: dots[b][j] = g_up . g_j (j < nact), fold into GGt
// (row/col up), then solve the bordered (nact+1) system -> alpha[b].
// One block per batch row; f32x4-vectorized loads. Replaces dots_kernel +
// solve_kernel (removes 29 dispatches, parallelizes solve over 2048 blocks).
// ---------------------------------------------------------------------------
__global__ __launch_bounds__(256) void dots_solve_kernel(
    const float* __restrict__ F, const float* __restrict__ X,
    const float* __restrict__ G, float* __restrict__ GGt,
    float* __restrict__ alpha, int up, int nact)
{
    const int b = blockIdx.x;
    const int tid = threadIdx.x;
    const size_t rb = (size_t)b * XROWS;
    float acc[MS];
#pragma unroll
    for (int p = 0; p < MS; p++) acc[p] = 0.0f;

    if (G) {
        const f32x4* Gb = (const f32x4*)(G + rb);
        for (int pos = tid; pos < DIM / 4; pos += 256) {
            f32x4 gu = Gb[up * (DIM / 4) + pos];
#pragma unroll
            for (int j = 0; j < MS; j++) {
                if (j < nact) {
                    f32x4 gj = (j == up) ? gu : Gb[j * (DIM / 4) + pos];
                    acc[j] = fmaf(gu.x, gj.x, acc[j]);
                    acc[j] = fmaf(gu.y, gj.y, acc[j]);
                    acc[j] = fmaf(gu.z, gj.z, acc[j]);
                    acc[j] = fmaf(gu.w, gj.w, acc[j]);
                }
            }
        }
    } else {
        const f32x4* Fb = (const f32x4*)(F + rb);
        const f32x4* Xb = (const f32x4*)(X + rb);
        for (int pos = tid; pos < DIM / 4; pos += 256) {
            f32x4 fu = Fb[up * (DIM / 4) + pos];
            f32x4 xu = Xb[up * (DIM / 4) + pos];
            f32x4 gu = fu - xu;
#pragma unroll
            for (int j = 0; j < MS; j++) {
                if (j < nact) {
                    f32x4 gj;
                    if (j == up) gj = gu;
                    else {
                        f32x4 fj = Fb[j * (DIM / 4) + pos];
                        f32x4 xj = Xb[j * (DIM / 4) + pos];
                        gj = fj - xj;
                    }
                    acc[j] = fmaf(gu.x, gj.x, acc[j]);
                    acc[j] = fmaf(gu.y, gj.y, acc[j]);
                    acc[j] = fmaf(gu.z, gj.z, acc[j]);
                    acc[j] = fmaf(gu.w, gj.w, acc[j]);
                }
            }
        }
    }

#pragma unroll
    for (int p = 0; p < MS; p++) {
        float v = acc[p];
#pragma unroll
        for (int off = 32; off > 0; off >>= 1) v += __shfl_down(v, off);
        acc[p] = v;
    }
    __shared__ float red[4][MS];
    __shared__ float Hs[7][8];
    __shared__ float sols[7];
    const int lane = tid & 63, wave = tid >> 6;
    if (lane == 0) {
#pragma unroll
        for (int p = 0; p < MS; p++) red[wave][p] = acc[p];
    }
    __syncthreads();
    if (tid == 0) {
        float d[MS];
#pragma unroll
        for (int j = 0; j < MS; j++)
            d[j] = red[0][j] + red[1][j] + red[2][j] + red[3][j];
        float* gg = GGt + (size_t)b * 36;
        for (int j = 0; j < nact; j++) {
            gg[up * 6 + j] = d[j];
            gg[j * 6 + up] = d[j];
        }
        const int np = nact + 1;
        for (int i = 0; i < np; i++) {
            for (int j = 0; j < np; j++) {
                float v;
                if (i == 0 && j == 0) v = 0.0f;
                else if (i == 0 || j == 0) v = 1.0f;
                else {
                    v = gg[(i - 1) * 6 + (j - 1)];
                    if (i == j) v += LAMREG;
                }
                Hs[i][j] = v;
            }
            Hs[i][7] = (i == 0) ? 1.0f : 0.0f;
        }
        for (int c = 0; c < np; c++) {
            int piv = c;
            float mx = fabsf(Hs[c][c]);
            for (int r = c + 1; r < np; r++) {
                float a = fabsf(Hs[r][c]);
                if (a > mx) { mx = a; piv = r; }
            }
            if (piv != c) {
                for (int cc = c; cc <= 7; cc++) {
                    float t = Hs[c][cc]; Hs[c][cc] = Hs[piv][cc]; Hs[piv][cc] = t;
                }
            }
            float inv = 1.0f / Hs[c][c];
            for (int r = c + 1; r < np; r++) {
                float f = Hs[r][c] * inv;
                for (int cc = c; cc <= 7; cc++) Hs[r][cc] -= f * Hs[c][cc];
            }
        }
        for (int c = np - 1; c >= 0; c--) {
            float s = Hs[c][7];
            for (int cc = c + 1; cc < np; cc++) s -= Hs[c][cc] * sols[cc];
            sols[c] = s / Hs[c][c];
        }
        for (int i = 0; i < nact; i++) alpha[(size_t)b * MS + i] = sols[i + 1];
    }
}

// ---------------------------------------------------------------------------
// xnew = sum_i alpha_i F[:,i] -> X[:,up] (f32) + split-bf16 GEMM input.
// f32x4-vectorized: one float4 per thread. Writes `result` on final iter.
// ---------------------------------------------------------------------------
__global__ __launch_bounds__(256) void xnew_kernel(
    const float* __restrict__ F, const float* __restrict__ alpha,
    float* __restrict__ Xout, __bf16* __restrict__ Ahi, __bf16* __restrict__ Alo,
    float* __restrict__ resultOrNull, int n, int up)
{
    const int idx = blockIdx.x * 256 + threadIdx.x;   // float4 index
    const int b = idx >> 9;                           // 512 float4 per row
    const int j4 = idx & 511;
    const float* al = alpha + (size_t)b * MS;
    const f32x4* fb = (const f32x4*)(F + (size_t)b * XROWS);
    f32x4 s = (f32x4){0.f, 0.f, 0.f, 0.f};
    for (int i = 0; i < n; i++) {
        f32x4 fv = fb[i * (DIM / 4) + j4];
        float a = al[i];
        s.x = fmaf(a, fv.x, s.x);
        s.y = fmaf(a, fv.y, s.y);
        s.z = fmaf(a, fv.z, s.z);
        s.w = fmaf(a, fv.w, s.w);
    }
    *(f32x4*)(Xout + (size_t)b * XROWS + (size_t)up * DIM + (size_t)j4 * 4) = s;
    if (resultOrNull) ((f32x4*)resultOrNull)[idx] = s;
    bf16x4 hh, ll;
#pragma unroll
    for (int c = 0; c < 4; c++) {
        float v = s[c];
        __bf16 h = (__bf16)v;
        hh[c] = h;
        ll[c] = (__bf16)(v - (float)h);
    }
    *(bf16x4*)&Ahi[(size_t)idx * 4] = hh;
    *(bf16x4*)&Alo[(size_t)idx * 4] = ll;
}

__global__ void finalize_kernel(const float* __restrict__ norms,
                                float* __restrict__ rel, float* __restrict__ absd)
{
    int t = threadIdx.x;
    if (t < NIT) {
        float a = sqrtf(norms[2 * t]);
        float fn = sqrtf(norms[2 * t + 1]);
        absd[t] = a;
        rel[t] = a / (1e-5f + fn);
    }
}

extern "C" void kernel_launch(void* const* d_in, const int* in_sizes, int n_in,
                              void* d_out, int out_size, void* d_ws, size_t ws_size,
                              hipStream_t stream) {
    const float* x0   = (const float*)d_in[0];
    const float* W    = (const float*)d_in[1];
    const float* bias = (const float*)d_in[2];

    float* out    = (float*)d_out;
    float* result = out;
    float* Xout   = out + (size_t)BSZ * DIM;
    float* rel    = Xout + (size_t)BSZ * MS * DIM;
    float* absd   = rel + NIT;

    char* ws = (char*)d_ws;
    float* F     = (float*)ws;                                   // 100.66 MB
    float* alpha = F + (size_t)BSZ * MS * DIM;                   // 48 KB
    float* norms = alpha + (size_t)BSZ * MS;                     // 256 B
    float* GGt   = norms + 64;                                   // 288 KB
    char* p = (char*)(GGt + (size_t)BSZ * 36);
    size_t off = ((size_t)(p - ws) + 255) & ~(size_t)255;
    __bf16* Ahi  = (__bf16*)(ws + off);  off += (size_t)BSZ * DIM * 2;
    __bf16* Alo  = (__bf16*)(ws + off);  off += (size_t)BSZ * DIM * 2;
    __bf16* WThi = (__bf16*)(ws + off);  off += (size_t)DIM * DIM * 2;
    __bf16* WTlo = (__bf16*)(ws + off);  off += (size_t)DIM * DIM * 2;
    // G array (100.66 MB) only if scratch is big enough
    float* G = nullptr;
    if (ws_size >= off + (size_t)BSZ * MS * DIM * 4 + 256) {
        off = (off + 255) & ~(size_t)255;
        G = (float*)(ws + off);
    }

    wt_split_kernel<<<dim3(64, 64), 256, 0, stream>>>(W, WThi, WTlo);
    init_kernel<<<2048, 256, 0, stream>>>(x0, Xout, Ahi, Alo, norms);
    // F[:,0] = f(x0), G[:,0] = f - x0
    gemm_mfma_kernel<<<512, 256, 0, stream>>>(Ahi, Alo, WThi, WTlo, bias,
                                              Xout, F, G, 0, nullptr, 0);
    // dots + GGt fold + solve -> alpha for k=1
    dots_solve_kernel<<<BSZ, 256, 0, stream>>>(F, Xout, G, GGt, alpha, 0, 1);
    for (int k = 1; k <= NIT; k++) {
        int n = (k < MS) ? k : MS;
        int up = k % MS;
        int nact = (k + 1 < MS) ? (k + 1) : MS;
        xnew_kernel<<<BSZ * DIM / 1024, 256, 0, stream>>>(F, alpha, Xout, Ahi, Alo,
                                                          (k == NIT) ? result : nullptr,
                                                          n, up);
        gemm_mfma_kernel<<<512, 256, 0, stream>>>(Ahi, Alo, WThi, WTlo, bias,
                                                  Xout, F, G, up,
                                                  norms + 2 * (k - 1), 1);
        if (k < NIT)
            dots_solve_kernel<<<BSZ, 256, 0, stream>>>(F, Xout, G, GGt, alpha, up, nact);
    }
    finalize_kernel<<<1, 64, 0, stream>>>(norms, rel, absd);
}